// Round 1
// baseline (3271.583 us; speedup 1.0000x reference)
//
#include <hip/hip_runtime.h>
#include <cmath>

// Problem constants (B,C,H,W)=(8,256,128,128), hidden=512, CHUNK=64
#define BATCH 8
#define CDIM 256
#define HWDIM 16384          // 128*128
#define MDIM 131072          // BATCH*HWDIM
#define HIDDEN 512

typedef unsigned short u16;
typedef unsigned int u32;

__device__ __forceinline__ float bfu(u16 u) {
    union { u32 i; float f; } p; p.i = ((u32)u) << 16; return p.f;
}
__device__ __forceinline__ float blo(u32 u) {
    union { u32 i; float f; } p; p.i = u << 16; return p.f;
}
__device__ __forceinline__ float bhi(u32 u) {
    union { u32 i; float f; } p; p.i = u & 0xFFFF0000u; return p.f;
}
__device__ __forceinline__ u16 fbf(float f) {   // fp32 -> bf16 RNE
    union { float f; u32 i; } p; p.f = f;
    u32 r = p.i + 0x7FFFu + ((p.i >> 16) & 1u);
    return (u16)(r >> 16);
}
__device__ __forceinline__ float gelu_f(float v) {
    return 0.5f * v * (1.0f + erff(v * 0.70710678118654752f));
}

// ---------------------------------------------------------------------------
// LayerNorm over channels: x (B,C,HW) fp32 NCHW -> out (B*HW, C) bf16 rows
// One thread per spatial position; loads coalesced along n across lanes.
__global__ __launch_bounds__(256) void ln_k(const float* __restrict__ x,
                                            const float* __restrict__ sc,
                                            const float* __restrict__ bi,
                                            u16* __restrict__ out)
{
    const int idx = blockIdx.x * 256 + threadIdx.x;   // 0..MDIM-1
    const int b = idx >> 14;
    const int n = idx & 16383;
    const float* xp = x + ((size_t)b << 22) + n;      // b*C*HW = b*2^22
    float s = 0.f, s2 = 0.f;
    for (int c = 0; c < CDIM; ++c) {
        const float v = xp[(size_t)c << 14];
        s += v; s2 += v * v;
    }
    const float mu = s * (1.f / CDIM);
    const float var = s2 * (1.f / CDIM) - mu * mu;
    const float r = rsqrtf(var + 1e-5f);
    u16* op = out + ((size_t)idx << 8);
    for (int c = 0; c < CDIM; c += 2) {
        const float v0 = (xp[(size_t)c << 14] - mu) * r * sc[c] + bi[c];
        const float v1 = (xp[(size_t)(c + 1) << 14] - mu) * r * sc[c + 1] + bi[c + 1];
        const u32 o = ((u32)fbf(v1) << 16) | fbf(v0);
        *(u32*)(op + c) = o;
    }
}

// ---------------------------------------------------------------------------
// Tiled GEMM: C(M x NN) = A(M x K) * Wt(NN x K)^T  (+ epilogues)
// AMODE 0: A is bf16 (M,K) row-major.  AMODE 1: A is bf16 NCHW (B, K, HW).
// EPI 0: +bias, store bf16 row-major (qkv)
// EPI 1: +bias +res(NCHW fp32), store fp32 NCHW (proj + shortcut -> x2)
// EPI 2: gelu(+bias), store bf16 NCHW (conv1)
// EPI 3: +bias +res(NCHW fp32), store fp32 NCHW (conv3 + x2 -> out, in-place ok)
template<int K, int NN, int AMODE, int EPI>
__global__ __launch_bounds__(256) void gemm_k(const u16* __restrict__ A,
                                              const float* __restrict__ Wt,
                                              const float* __restrict__ bias,
                                              const float* __restrict__ res,
                                              float* __restrict__ outF,
                                              u16* __restrict__ outB)
{
    __shared__ float As[16][68];
    __shared__ float Bs[16][68];
    const int t = threadIdx.x;
    const int m0 = blockIdx.x * 64;
    const int j0 = blockIdx.y * 64;
    const int ty = t >> 4, tx = t & 15;
    const int bb = m0 >> 14;
    const int n0 = m0 & 16383;
    float acc[4][4] = {};

    for (int k0 = 0; k0 < K; k0 += 16) {
        if constexpr (AMODE == 0) {
            const int row = t >> 2, kq = (t & 3) * 4;
            const u16* ap = A + (size_t)(m0 + row) * K + (k0 + kq);
            const ushort4 u = *(const ushort4*)ap;
            As[kq + 0][row] = bfu(u.x);
            As[kq + 1][row] = bfu(u.y);
            As[kq + 2][row] = bfu(u.z);
            As[kq + 3][row] = bfu(u.w);
        } else {
            const int mloc = t & 63, khi = t >> 6;
            #pragma unroll
            for (int p = 0; p < 4; ++p) {
                const int kl = khi * 4 + p;
                As[kl][mloc] = bfu(A[((size_t)(bb * K + k0 + kl) << 14) + n0 + mloc]);
            }
        }
        {
            const int j = t >> 2, kq = (t & 3) * 4;
            const float4 w = *(const float4*)(Wt + (size_t)(j0 + j) * K + (k0 + kq));
            Bs[kq + 0][j] = w.x;
            Bs[kq + 1][j] = w.y;
            Bs[kq + 2][j] = w.z;
            Bs[kq + 3][j] = w.w;
        }
        __syncthreads();
        #pragma unroll
        for (int kk = 0; kk < 16; ++kk) {
            const float4 av = *(const float4*)&As[kk][ty * 4];
            const float4 bv = *(const float4*)&Bs[kk][tx * 4];
            const float aa[4] = { av.x, av.y, av.z, av.w };
            const float bb4[4] = { bv.x, bv.y, bv.z, bv.w };
            #pragma unroll
            for (int i = 0; i < 4; ++i)
                #pragma unroll
                for (int j = 0; j < 4; ++j)
                    acc[i][j] = fmaf(aa[i], bb4[j], acc[i][j]);
        }
        __syncthreads();
    }

    #pragma unroll
    for (int i = 0; i < 4; ++i) {
        const int m = m0 + ty * 4 + i;
        const int bb2 = m >> 14;
        const int n = m & 16383;
        #pragma unroll
        for (int jj = 0; jj < 4; ++jj) {
            const int j = j0 + tx * 4 + jj;
            const float v = acc[i][jj] + bias[j];
            if constexpr (EPI == 0) {
                outB[(size_t)m * NN + j] = fbf(v);
            } else if constexpr (EPI == 1) {
                const size_t idx = (((size_t)(bb2 * NN + j)) << 14) + n;
                outF[idx] = v + res[idx];
            } else if constexpr (EPI == 2) {
                const size_t idx = (((size_t)(bb2 * NN + j)) << 14) + n;
                outB[idx] = fbf(gelu_f(v));
            } else {
                const size_t idx = (((size_t)(bb2 * NN + j)) << 14) + n;
                outF[idx] = v + res[idx];
            }
        }
    }
}

// ---------------------------------------------------------------------------
// Chunked attention: one workgroup per (b, chunk) = 64 rows of qkv (M,768) bf16.
// scores/softmax in fp32 LDS, K/V staged as bf16 in LDS. Output bf16 (M,256).
__global__ __launch_bounds__(256) void attn_k(const u16* __restrict__ qkv,
                                              u16* __restrict__ ao)
{
    __shared__ u16 kvh[64][258];   // pad -> 129 words/row: 2-way banks max
    __shared__ float sc[64][67];
    const int t = threadIdx.x;
    const size_t base = (size_t)blockIdx.x * 64;

    // stage K (bf16 pairs, coalesced)
    for (int p = t; p < 8192; p += 256) {
        const int r = p >> 7, c2 = p & 127;
        *(u32*)&kvh[r][c2 * 2] = *(const u32*)(qkv + (base + r) * 768 + 256 + c2 * 2);
    }
    __syncthreads();

    // scores: thread t -> row i = t/4, 16 cols starting (t%4)*16
    {
        const int i = t >> 2, jb = (t & 3) * 16;
        float acc[16] = {};
        const u16* qp = qkv + (base + i) * 768;
        for (int c = 0; c < 256; c += 2) {
            const u32 qu = *(const u32*)(qp + c);
            const float q0 = blo(qu), q1 = bhi(qu);
            #pragma unroll
            for (int j = 0; j < 16; ++j) {
                const u32 ku = *(const u32*)&kvh[jb + j][c];
                acc[j] = fmaf(q0, blo(ku), acc[j]);
                acc[j] = fmaf(q1, bhi(ku), acc[j]);
            }
        }
        #pragma unroll
        for (int j = 0; j < 16; ++j) sc[i][jb + j] = acc[j] * 0.0625f;
    }
    __syncthreads();

    // stage V over K (kvh free now), then softmax rows (threads 0..63, sc only)
    for (int p = t; p < 8192; p += 256) {
        const int r = p >> 7, c2 = p & 127;
        *(u32*)&kvh[r][c2 * 2] = *(const u32*)(qkv + (base + r) * 768 + 512 + c2 * 2);
    }
    if (t < 64) {
        float mx = -1e30f;
        for (int j = 0; j < 64; ++j) mx = fmaxf(mx, sc[t][j]);
        float s = 0.f;
        for (int j = 0; j < 64; ++j) {
            const float e = expf(sc[t][j] - mx);
            sc[t][j] = e; s += e;
        }
        const float inv = 1.f / s;
        for (int j = 0; j < 64; ++j) sc[t][j] *= inv;
    }
    __syncthreads();

    // out[i][c] = sum_j P[i][j] * V[j][c]; thread handles 2 cols x 32 rows
    {
        const int ch = t & 127;            // column pair index
        const int ih = (t >> 7) * 32;      // row half
        for (int i2 = ih; i2 < ih + 32; ++i2) {
            float a0 = 0.f, a1 = 0.f;
            #pragma unroll
            for (int j = 0; j < 64; ++j) {
                const float p = sc[i2][j];
                const u32 vu = *(const u32*)&kvh[j][ch * 2];
                a0 = fmaf(p, blo(vu), a0);
                a1 = fmaf(p, bhi(vu), a1);
            }
            const u32 o = ((u32)fbf(a1) << 16) | fbf(a0);
            *(u32*)(ao + (base + i2) * 256 + ch * 2) = o;
        }
    }
}

// ---------------------------------------------------------------------------
// Depthwise 3x3 conv (pad 1) + bias + GELU, NCHW bf16 -> bf16
__global__ __launch_bounds__(256) void dwconv_k(const u16* __restrict__ h1,
                                                const float* __restrict__ w,
                                                const float* __restrict__ b2,
                                                u16* __restrict__ h2)
{
    const int g = blockIdx.x * 256 + threadIdx.x;  // over BATCH*HIDDEN*HW
    const int x = g & 127;
    const int y = (g >> 7) & 127;
    const int bo = g >> 14;
    const int o = bo & (HIDDEN - 1);
    const u16* in = h1 + ((size_t)bo << 14);
    const float* wp = w + o * 9;
    float a = 0.f;
    #pragma unroll
    for (int dy = -1; dy <= 1; ++dy) {
        const int yy = y + dy;
        if (yy < 0 || yy > 127) continue;
        #pragma unroll
        for (int dx = -1; dx <= 1; ++dx) {
            const int xx = x + dx;
            if (xx < 0 || xx > 127) continue;
            a = fmaf(wp[(dy + 1) * 3 + (dx + 1)], bfu(in[(yy << 7) + xx]), a);
        }
    }
    a += b2[o];
    h2[g] = fbf(gelu_f(a));
}

// ---------------------------------------------------------------------------
extern "C" void kernel_launch(void* const* d_in, const int* in_sizes, int n_in,
                              void* d_out, int out_size, void* d_ws, size_t ws_size,
                              hipStream_t stream)
{
    (void)in_sizes; (void)n_in; (void)out_size; (void)ws_size;
    const float* x     = (const float*)d_in[0];
    const float* ln1s  = (const float*)d_in[1];
    const float* ln1b  = (const float*)d_in[2];
    const float* qkvw  = (const float*)d_in[3];
    const float* qkvb  = (const float*)d_in[4];
    const float* projw = (const float*)d_in[5];
    const float* projb = (const float*)d_in[6];
    const float* ln2s  = (const float*)d_in[7];
    const float* ln2b  = (const float*)d_in[8];
    const float* w1    = (const float*)d_in[9];
    const float* b1    = (const float*)d_in[10];
    const float* w2    = (const float*)d_in[11];
    const float* b2    = (const float*)d_in[12];
    const float* w3    = (const float*)d_in[13];
    const float* b3    = (const float*)d_in[14];
    float* out = (float*)d_out;
    char* ws = (char*)d_ws;

    // workspace plan (bytes): needs 320 MiB total
    //  XLN  [0,        64Mi)  bf16 (M,256)   -> later reused as YLN
    //  QKV  [64Mi,    256Mi)  bf16 (M,768)   -> later reused as H1 (first 128Mi)
    //  AO   [256Mi,   320Mi)  bf16 (M,256)   -> later part of H2
    //  H1   [64Mi,    192Mi)  bf16 NCHW (B,512,HW)
    //  H2   [192Mi,   320Mi)  bf16 NCHW (B,512,HW)
    //  X2 lives in d_out (fp32 NCHW), final kernel adds in-place.
    u16* XLN = (u16*)(ws);
    u16* QKV = (u16*)(ws + (size_t)67108864);
    u16* AO  = (u16*)(ws + (size_t)268435456);
    u16* YLN = XLN;
    u16* H1  = (u16*)(ws + (size_t)67108864);
    u16* H2  = (u16*)(ws + (size_t)201326592);

    ln_k<<<dim3(MDIM / 256), dim3(256), 0, stream>>>(x, ln1s, ln1b, XLN);
    gemm_k<256, 768, 0, 0><<<dim3(MDIM / 64, 12), dim3(256), 0, stream>>>(XLN, qkvw, qkvb, nullptr, nullptr, QKV);
    attn_k<<<dim3(MDIM / 64), dim3(256), 0, stream>>>(QKV, AO);
    gemm_k<256, 256, 0, 1><<<dim3(MDIM / 64, 4), dim3(256), 0, stream>>>(AO, projw, projb, x, out, nullptr);
    ln_k<<<dim3(MDIM / 256), dim3(256), 0, stream>>>(out, ln2s, ln2b, YLN);
    gemm_k<256, 512, 0, 2><<<dim3(MDIM / 64, 8), dim3(256), 0, stream>>>(YLN, w1, b1, nullptr, nullptr, H1);
    dwconv_k<<<dim3((BATCH * HIDDEN * HWDIM) / 256), dim3(256), 0, stream>>>(H1, w2, b2, H2);
    gemm_k<512, 256, 1, 3><<<dim3(MDIM / 64, 4), dim3(256), 0, stream>>>(H2, w3, b3, out, out, nullptr);
}

// Round 2
// 1894.237 us; speedup vs baseline: 1.7271x; 1.7271x over previous
//
#include <hip/hip_runtime.h>
#include <cmath>

// (B,C,H,W)=(8,256,128,128), hidden=512, CHUNK=64
#define BATCH 8
#define CDIM 256
#define HWDIM 16384
#define MDIM 131072
#define HIDDEN 512

typedef unsigned short u16;
typedef unsigned int u32;
typedef short bf16x8 __attribute__((ext_vector_type(8)));
typedef float floatx4 __attribute__((ext_vector_type(4)));
typedef __attribute__((address_space(3))) unsigned int as3_u32;
typedef __attribute__((address_space(1))) const unsigned int as1_u32;

__device__ __forceinline__ float bfu(u16 u) {
    union { u32 i; float f; } p; p.i = ((u32)u) << 16; return p.f;
}
__device__ __forceinline__ float blo(u32 u) {
    union { u32 i; float f; } p; p.i = u << 16; return p.f;
}
__device__ __forceinline__ float bhi(u32 u) {
    union { u32 i; float f; } p; p.i = u & 0xFFFF0000u; return p.f;
}
__device__ __forceinline__ u16 fbf(float f) {   // fp32 -> bf16 RNE
    union { float f; u32 i; } p; p.f = f;
    u32 r = p.i + 0x7FFFu + ((p.i >> 16) & 1u);
    return (u16)(r >> 16);
}
__device__ __forceinline__ float gelu_f(float v) {
    return 0.5f * v * (1.0f + erff(v * 0.70710678118654752f));
}
__device__ __forceinline__ void gl_lds16(const u16* g, u16* l) {
    __builtin_amdgcn_global_load_lds((as1_u32*)(const void*)g,
                                     (as3_u32*)(void*)l, 16, 0, 0);
}

// ---------------------------------------------------------------------------
// LayerNorm over channels: x (B,C,HW) fp32 NCHW -> out (B*HW, C) bf16 rows
__global__ __launch_bounds__(256) void ln_k(const float* __restrict__ x,
                                            const float* __restrict__ sc,
                                            const float* __restrict__ bi,
                                            u16* __restrict__ out)
{
    const int idx = blockIdx.x * 256 + threadIdx.x;
    const int b = idx >> 14;
    const int n = idx & 16383;
    const float* xp = x + ((size_t)b << 22) + n;
    float s = 0.f, s2 = 0.f;
    for (int c = 0; c < CDIM; ++c) {
        const float v = xp[(size_t)c << 14];
        s += v; s2 += v * v;
    }
    const float mu = s * (1.f / CDIM);
    const float var = s2 * (1.f / CDIM) - mu * mu;
    const float r = rsqrtf(var + 1e-5f);
    u16* op = out + ((size_t)idx << 8);
    for (int c = 0; c < CDIM; c += 2) {
        const float v0 = (xp[(size_t)c << 14] - mu) * r * sc[c] + bi[c];
        const float v1 = (xp[(size_t)(c + 1) << 14] - mu) * r * sc[c + 1] + bi[c + 1];
        const u32 o = ((u32)fbf(v1) << 16) | fbf(v0);
        *(u32*)(op + c) = o;
    }
}

// ---------------------------------------------------------------------------
// MFMA GEMM: C(M x NN) = A(M x K, bf16 row-major) * Wt(NN x K, fp32)^T
// Tile 128(M) x 64(N) x 64(K). 4 waves, each 64x32 via 4x2 mfma_16x16x32_bf16.
// A staged with global_load_lds (16B, XOR-swizzled chunks); B converted
// fp32->bf16 in-register during staging.
// EPI 0: +bias -> bf16 row-major (LDS-transposed coalesced store)
// EPI 1: +bias +res(fp32 NCHW) -> fp32 NCHW
// EPI 2: gelu(+bias) -> bf16 row-major
// EPI 3: same as 1 (in-place residual ok)
template<int K, int NN, int EPI>
__global__ __launch_bounds__(256) void mgemm(const u16* __restrict__ A,
                                             const float* __restrict__ Wt,
                                             const float* __restrict__ bias,
                                             const float* __restrict__ res,
                                             float* __restrict__ outF,
                                             u16* __restrict__ outB)
{
    __shared__ u16 smem[12288];          // As 128x64 (16KB) + Bs 64x64 (8KB)
    u16* As = smem;
    u16* Bs = smem + 8192;
    const int t = threadIdx.x;
    const int l = t & 63, w = t >> 6;
    const int m0 = blockIdx.x * 128;
    const int j0 = blockIdx.y * 64;
    const int wm = (w >> 1) * 64, wn = (w & 1) * 32;
    floatx4 acc[4][2] = {};

    for (int k0 = 0; k0 < K; k0 += 64) {
        // A tile: 1024 16B chunks; physical chunk pq holds logical kq=pq^(r&7)
        #pragma unroll
        for (int it = 0; it < 4; ++it) {
            const int q = it * 256 + t;
            const int r = q >> 3, pq = q & 7;
            const int kq = pq ^ (r & 7);
            const u16* g = A + (size_t)(m0 + r) * K + k0 + kq * 8;
            gl_lds16(g, As + (size_t)(it * 256 + w * 64) * 8);  // base wave-uniform
        }
        // B tile: 512 chunks, fp32 -> bf16 through VGPRs
        #pragma unroll
        for (int it = 0; it < 2; ++it) {
            const int q = it * 256 + t;
            const int r = q >> 3, pq = q & 7;
            const int kq = pq ^ (r & 7);
            const float* g = Wt + (size_t)(j0 + r) * K + k0 + kq * 8;
            const float4 w0 = *(const float4*)g;
            const float4 w1 = *(const float4*)(g + 4);
            uint4 pk;
            pk.x = ((u32)fbf(w0.y) << 16) | fbf(w0.x);
            pk.y = ((u32)fbf(w0.w) << 16) | fbf(w0.z);
            pk.z = ((u32)fbf(w1.y) << 16) | fbf(w1.x);
            pk.w = ((u32)fbf(w1.w) << 16) | fbf(w1.z);
            *(uint4*)(Bs + q * 8) = pk;
        }
        __syncthreads();
        #pragma unroll
        for (int ks = 0; ks < 2; ++ks) {
            bf16x8 af[4], bfr[2];
            const int kq = ks * 4 + (l >> 4);
            #pragma unroll
            for (int mi = 0; mi < 4; ++mi) {
                const int r = wm + mi * 16 + (l & 15);
                const int pq = kq ^ (r & 7);
                af[mi] = *(const bf16x8*)(As + r * 64 + pq * 8);
            }
            #pragma unroll
            for (int ni = 0; ni < 2; ++ni) {
                const int r = wn + ni * 16 + (l & 15);
                const int pq = kq ^ (r & 7);
                bfr[ni] = *(const bf16x8*)(Bs + r * 64 + pq * 8);
            }
            #pragma unroll
            for (int mi = 0; mi < 4; ++mi)
                #pragma unroll
                for (int ni = 0; ni < 2; ++ni)
                    acc[mi][ni] = __builtin_amdgcn_mfma_f32_16x16x32_bf16(
                        af[mi], bfr[ni], acc[mi][ni], 0, 0, 0);
        }
        __syncthreads();
    }

    // bias per lane column
    float bv[2];
    #pragma unroll
    for (int ni = 0; ni < 2; ++ni)
        bv[ni] = bias[j0 + wn + ni * 16 + (l & 15)];

    if constexpr (EPI == 0 || EPI == 2) {
        // LDS transpose: Cs[128][64] bf16 with col-chunk swizzle
        u16* Cs = smem;
        #pragma unroll
        for (int mi = 0; mi < 4; ++mi) {
            #pragma unroll
            for (int ni = 0; ni < 2; ++ni) {
                const int col = wn + ni * 16 + (l & 15);
                #pragma unroll
                for (int r = 0; r < 4; ++r) {
                    const int row = wm + mi * 16 + (l >> 4) * 4 + r;
                    float v = acc[mi][ni][r] + bv[ni];
                    if constexpr (EPI == 2) v = gelu_f(v);
                    const int pc = ((col >> 3) ^ (row & 7)) * 8 + (col & 7);
                    Cs[row * 64 + pc] = fbf(v);
                }
            }
        }
        __syncthreads();
        #pragma unroll
        for (int it = 0; it < 4; ++it) {
            const int q = it * 256 + t;
            const int row = q >> 3, pcq = q & 7;
            const int cq = pcq ^ (row & 7);
            *(uint4*)(outB + (size_t)(m0 + row) * NN + j0 + cq * 8) =
                *(const uint4*)(Cs + q * 8);
        }
    } else {
        #pragma unroll
        for (int mi = 0; mi < 4; ++mi) {
            const int m = m0 + wm + mi * 16 + (l >> 4) * 4;
            const int b = m >> 14, n = m & 16383;
            #pragma unroll
            for (int ni = 0; ni < 2; ++ni) {
                const int j = j0 + wn + ni * 16 + (l & 15);
                const size_t idx = ((size_t)(b * NN + j) << 14) + n;
                const float4 rv = *(const float4*)(res + idx);
                float4 o;
                o.x = acc[mi][ni][0] + bv[ni] + rv.x;
                o.y = acc[mi][ni][1] + bv[ni] + rv.y;
                o.z = acc[mi][ni][2] + bv[ni] + rv.z;
                o.w = acc[mi][ni][3] + bv[ni] + rv.w;
                *(float4*)(outF + idx) = o;
            }
        }
    }
}

// ---------------------------------------------------------------------------
// Chunked attention (unchanged this round)
__global__ __launch_bounds__(256) void attn_k(const u16* __restrict__ qkv,
                                              u16* __restrict__ ao)
{
    __shared__ u16 kvh[64][258];
    __shared__ float sc[64][67];
    const int t = threadIdx.x;
    const size_t base = (size_t)blockIdx.x * 64;

    for (int p = t; p < 8192; p += 256) {
        const int r = p >> 7, c2 = p & 127;
        *(u32*)&kvh[r][c2 * 2] = *(const u32*)(qkv + (base + r) * 768 + 256 + c2 * 2);
    }
    __syncthreads();
    {
        const int i = t >> 2, jb = (t & 3) * 16;
        float acc[16] = {};
        const u16* qp = qkv + (base + i) * 768;
        for (int c = 0; c < 256; c += 2) {
            const u32 qu = *(const u32*)(qp + c);
            const float q0 = blo(qu), q1 = bhi(qu);
            #pragma unroll
            for (int j = 0; j < 16; ++j) {
                const u32 ku = *(const u32*)&kvh[jb + j][c];
                acc[j] = fmaf(q0, blo(ku), acc[j]);
                acc[j] = fmaf(q1, bhi(ku), acc[j]);
            }
        }
        #pragma unroll
        for (int j = 0; j < 16; ++j) sc[i][jb + j] = acc[j] * 0.0625f;
    }
    __syncthreads();
    for (int p = t; p < 8192; p += 256) {
        const int r = p >> 7, c2 = p & 127;
        *(u32*)&kvh[r][c2 * 2] = *(const u32*)(qkv + (base + r) * 768 + 512 + c2 * 2);
    }
    if (t < 64) {
        float mx = -1e30f;
        for (int j = 0; j < 64; ++j) mx = fmaxf(mx, sc[t][j]);
        float s = 0.f;
        for (int j = 0; j < 64; ++j) {
            const float e = expf(sc[t][j] - mx);
            sc[t][j] = e; s += e;
        }
        const float inv = 1.f / s;
        for (int j = 0; j < 64; ++j) sc[t][j] *= inv;
    }
    __syncthreads();
    {
        const int ch = t & 127;
        const int ih = (t >> 7) * 32;
        for (int i2 = ih; i2 < ih + 32; ++i2) {
            float a0 = 0.f, a1 = 0.f;
            #pragma unroll
            for (int j = 0; j < 64; ++j) {
                const float p = sc[i2][j];
                const u32 vu = *(const u32*)&kvh[j][ch * 2];
                a0 = fmaf(p, blo(vu), a0);
                a1 = fmaf(p, bhi(vu), a1);
            }
            const u32 o = ((u32)fbf(a1) << 16) | fbf(a0);
            *(u32*)(ao + (base + i2) * 256 + ch * 2) = o;
        }
    }
}

// ---------------------------------------------------------------------------
// Depthwise 3x3 + bias + GELU on CHANNEL-LAST bf16 (M,512) -> (M,512)
__global__ __launch_bounds__(256) void dwconv_cl(const u16* __restrict__ h1,
                                                 const float* __restrict__ w,
                                                 const float* __restrict__ b2,
                                                 u16* __restrict__ h2)
{
    const int g = blockIdx.x * 256 + threadIdx.x;   // over M*512
    const int c = g & 511;
    const int n = g >> 9;
    const int x = n & 127, y = (n >> 7) & 127, b = n >> 14;
    const u16* in = h1 + ((size_t)b << 14) * 512 + c;
    const float* wp = w + c * 9;
    float a = 0.f;
    #pragma unroll
    for (int dy = -1; dy <= 1; ++dy) {
        const int yy = y + dy;
        if (yy < 0 || yy > 127) continue;
        #pragma unroll
        for (int dx = -1; dx <= 1; ++dx) {
            const int xx = x + dx;
            if (xx < 0 || xx > 127) continue;
            a = fmaf(wp[(dy + 1) * 3 + (dx + 1)], bfu(in[(size_t)((yy << 7) + xx) * 512]), a);
        }
    }
    a += b2[c];
    h2[g] = fbf(gelu_f(a));
}

// ---------------------------------------------------------------------------
extern "C" void kernel_launch(void* const* d_in, const int* in_sizes, int n_in,
                              void* d_out, int out_size, void* d_ws, size_t ws_size,
                              hipStream_t stream)
{
    (void)in_sizes; (void)n_in; (void)out_size; (void)ws_size;
    const float* x     = (const float*)d_in[0];
    const float* ln1s  = (const float*)d_in[1];
    const float* ln1b  = (const float*)d_in[2];
    const float* qkvw  = (const float*)d_in[3];
    const float* qkvb  = (const float*)d_in[4];
    const float* projw = (const float*)d_in[5];
    const float* projb = (const float*)d_in[6];
    const float* ln2s  = (const float*)d_in[7];
    const float* ln2b  = (const float*)d_in[8];
    const float* w1    = (const float*)d_in[9];
    const float* b1    = (const float*)d_in[10];
    const float* w2    = (const float*)d_in[11];
    const float* b2    = (const float*)d_in[12];
    const float* w3    = (const float*)d_in[13];
    const float* b3    = (const float*)d_in[14];
    float* out = (float*)d_out;
    char* ws = (char*)d_ws;

    // workspace (320 MiB):
    //  XLN/YLN [0,64Mi) bf16 (M,256)
    //  QKV [64Mi,256Mi) bf16 (M,768) -> later H1 [64Mi,192Mi) bf16 (M,512)
    //  AO [256Mi,320Mi) bf16 (M,256) -> later tail of H2 [192Mi,320Mi)
    u16* XLN = (u16*)(ws);
    u16* QKV = (u16*)(ws + (size_t)67108864);
    u16* AO  = (u16*)(ws + (size_t)268435456);
    u16* YLN = XLN;
    u16* H1  = (u16*)(ws + (size_t)67108864);
    u16* H2  = (u16*)(ws + (size_t)201326592);

    ln_k<<<dim3(MDIM / 256), dim3(256), 0, stream>>>(x, ln1s, ln1b, XLN);
    mgemm<256, 768, 0><<<dim3(1024, 12), dim3(256), 0, stream>>>(XLN, qkvw, qkvb, nullptr, nullptr, QKV);
    attn_k<<<dim3(MDIM / 64), dim3(256), 0, stream>>>(QKV, AO);
    mgemm<256, 256, 1><<<dim3(1024, 4), dim3(256), 0, stream>>>(AO, projw, projb, x, out, nullptr);
    ln_k<<<dim3(MDIM / 256), dim3(256), 0, stream>>>(out, ln2s, ln2b, YLN);
    mgemm<256, 512, 2><<<dim3(1024, 8), dim3(256), 0, stream>>>(YLN, w1, b1, nullptr, nullptr, H1);
    dwconv_cl<<<dim3((MDIM * 512) / 256), dim3(256), 0, stream>>>(H1, w2, b2, H2);
    mgemm<512, 256, 3><<<dim3(1024, 4), dim3(256), 0, stream>>>(H2, w3, b3, out, out, nullptr);
}

// Round 3
// 1551.789 us; speedup vs baseline: 2.1083x; 1.2207x over previous
//
#include <hip/hip_runtime.h>
#include <cmath>

// (B,C,H,W)=(8,256,128,128), hidden=512, CHUNK=64
#define BATCH 8
#define CDIM 256
#define HWDIM 16384
#define MDIM 131072
#define HIDDEN 512

typedef unsigned short u16;
typedef unsigned int u32;
typedef short bf16x8 __attribute__((ext_vector_type(8)));
typedef float floatx4 __attribute__((ext_vector_type(4)));
typedef __attribute__((address_space(3))) unsigned int as3_u32;
typedef __attribute__((address_space(1))) const unsigned int as1_u32;

__device__ __forceinline__ float bfu(u16 u) {
    union { u32 i; float f; } p; p.i = ((u32)u) << 16; return p.f;
}
__device__ __forceinline__ float blo(u32 u) {
    union { u32 i; float f; } p; p.i = u << 16; return p.f;
}
__device__ __forceinline__ float bhi(u32 u) {
    union { u32 i; float f; } p; p.i = u & 0xFFFF0000u; return p.f;
}
__device__ __forceinline__ u16 fbf(float f) {   // fp32 -> bf16 RNE
    union { float f; u32 i; } p; p.f = f;
    u32 r = p.i + 0x7FFFu + ((p.i >> 16) & 1u);
    return (u16)(r >> 16);
}
__device__ __forceinline__ float gelu_f(float v) {
    return 0.5f * v * (1.0f + erff(v * 0.70710678118654752f));
}
__device__ __forceinline__ void gl_lds16(const u16* g, u16* l) {
    __builtin_amdgcn_global_load_lds((as1_u32*)(const void*)g,
                                     (as3_u32*)(void*)l, 16, 0, 0);
}

// ---------------------------------------------------------------------------
// LayerNorm over channels: x (B,C,HW) fp32 NCHW -> out (B*HW, C) bf16 rows
__global__ __launch_bounds__(256) void ln_k(const float* __restrict__ x,
                                            const float* __restrict__ sc,
                                            const float* __restrict__ bi,
                                            u16* __restrict__ out)
{
    const int idx = blockIdx.x * 256 + threadIdx.x;
    const int b = idx >> 14;
    const int n = idx & 16383;
    const float* xp = x + ((size_t)b << 22) + n;
    float s = 0.f, s2 = 0.f;
    for (int c = 0; c < CDIM; ++c) {
        const float v = xp[(size_t)c << 14];
        s += v; s2 += v * v;
    }
    const float mu = s * (1.f / CDIM);
    const float var = s2 * (1.f / CDIM) - mu * mu;
    const float r = rsqrtf(var + 1e-5f);
    u16* op = out + ((size_t)idx << 8);
    for (int c = 0; c < CDIM; c += 2) {
        const float v0 = (xp[(size_t)c << 14] - mu) * r * sc[c] + bi[c];
        const float v1 = (xp[(size_t)(c + 1) << 14] - mu) * r * sc[c + 1] + bi[c + 1];
        const u32 o = ((u32)fbf(v1) << 16) | fbf(v0);
        *(u32*)(op + c) = o;
    }
}

// ---------------------------------------------------------------------------
// MFMA GEMM: C(M x NN) = A(M x K, bf16 row-major) * Wt(NN x K, fp32)^T
// Tile 128(M) x 64(N) x 64(K). 4 waves, each 64x32 via 4x2 mfma_16x16x32_bf16.
template<int K, int NN, int EPI>
__global__ __launch_bounds__(256) void mgemm(const u16* __restrict__ A,
                                             const float* __restrict__ Wt,
                                             const float* __restrict__ bias,
                                             const float* __restrict__ res,
                                             float* __restrict__ outF,
                                             u16* __restrict__ outB)
{
    __shared__ u16 smem[12288];          // As 128x64 (16KB) + Bs 64x64 (8KB)
    u16* As = smem;
    u16* Bs = smem + 8192;
    const int t = threadIdx.x;
    const int l = t & 63, w = t >> 6;
    const int m0 = blockIdx.x * 128;
    const int j0 = blockIdx.y * 64;
    const int wm = (w >> 1) * 64, wn = (w & 1) * 32;
    floatx4 acc[4][2] = {};

    for (int k0 = 0; k0 < K; k0 += 64) {
        #pragma unroll
        for (int it = 0; it < 4; ++it) {
            const int q = it * 256 + t;
            const int r = q >> 3, pq = q & 7;
            const int kq = pq ^ (r & 7);
            const u16* g = A + (size_t)(m0 + r) * K + k0 + kq * 8;
            gl_lds16(g, As + (size_t)(it * 256 + w * 64) * 8);
        }
        #pragma unroll
        for (int it = 0; it < 2; ++it) {
            const int q = it * 256 + t;
            const int r = q >> 3, pq = q & 7;
            const int kq = pq ^ (r & 7);
            const float* g = Wt + (size_t)(j0 + r) * K + k0 + kq * 8;
            const float4 w0 = *(const float4*)g;
            const float4 w1 = *(const float4*)(g + 4);
            uint4 pk;
            pk.x = ((u32)fbf(w0.y) << 16) | fbf(w0.x);
            pk.y = ((u32)fbf(w0.w) << 16) | fbf(w0.z);
            pk.z = ((u32)fbf(w1.y) << 16) | fbf(w1.x);
            pk.w = ((u32)fbf(w1.w) << 16) | fbf(w1.z);
            *(uint4*)(Bs + q * 8) = pk;
        }
        __syncthreads();
        #pragma unroll
        for (int ks = 0; ks < 2; ++ks) {
            bf16x8 af[4], bfr[2];
            const int kq = ks * 4 + (l >> 4);
            #pragma unroll
            for (int mi = 0; mi < 4; ++mi) {
                const int r = wm + mi * 16 + (l & 15);
                const int pq = kq ^ (r & 7);
                af[mi] = *(const bf16x8*)(As + r * 64 + pq * 8);
            }
            #pragma unroll
            for (int ni = 0; ni < 2; ++ni) {
                const int r = wn + ni * 16 + (l & 15);
                const int pq = kq ^ (r & 7);
                bfr[ni] = *(const bf16x8*)(Bs + r * 64 + pq * 8);
            }
            #pragma unroll
            for (int mi = 0; mi < 4; ++mi)
                #pragma unroll
                for (int ni = 0; ni < 2; ++ni)
                    acc[mi][ni] = __builtin_amdgcn_mfma_f32_16x16x32_bf16(
                        af[mi], bfr[ni], acc[mi][ni], 0, 0, 0);
        }
        __syncthreads();
    }

    float bv[2];
    #pragma unroll
    for (int ni = 0; ni < 2; ++ni)
        bv[ni] = bias[j0 + wn + ni * 16 + (l & 15)];

    if constexpr (EPI == 0 || EPI == 2) {
        u16* Cs = smem;
        #pragma unroll
        for (int mi = 0; mi < 4; ++mi) {
            #pragma unroll
            for (int ni = 0; ni < 2; ++ni) {
                const int col = wn + ni * 16 + (l & 15);
                #pragma unroll
                for (int r = 0; r < 4; ++r) {
                    const int row = wm + mi * 16 + (l >> 4) * 4 + r;
                    float v = acc[mi][ni][r] + bv[ni];
                    if constexpr (EPI == 2) v = gelu_f(v);
                    const int pc = ((col >> 3) ^ (row & 7)) * 8 + (col & 7);
                    Cs[row * 64 + pc] = fbf(v);
                }
            }
        }
        __syncthreads();
        #pragma unroll
        for (int it = 0; it < 4; ++it) {
            const int q = it * 256 + t;
            const int row = q >> 3, pcq = q & 7;
            const int cq = pcq ^ (row & 7);
            *(uint4*)(outB + (size_t)(m0 + row) * NN + j0 + cq * 8) =
                *(const uint4*)(Cs + q * 8);
        }
    } else {
        #pragma unroll
        for (int mi = 0; mi < 4; ++mi) {
            const int m = m0 + wm + mi * 16 + (l >> 4) * 4;
            const int b = m >> 14, n = m & 16383;
            #pragma unroll
            for (int ni = 0; ni < 2; ++ni) {
                const int j = j0 + wn + ni * 16 + (l & 15);
                const size_t idx = ((size_t)(b * NN + j) << 14) + n;
                const float4 rv = *(const float4*)(res + idx);
                float4 o;
                o.x = acc[mi][ni][0] + bv[ni] + rv.x;
                o.y = acc[mi][ni][1] + bv[ni] + rv.y;
                o.z = acc[mi][ni][2] + bv[ni] + rv.z;
                o.w = acc[mi][ni][3] + bv[ni] + rv.w;
                *(float4*)(outF + idx) = o;
            }
        }
    }
}

// ---------------------------------------------------------------------------
// Chunked attention (unchanged this round)
__global__ __launch_bounds__(256) void attn_k(const u16* __restrict__ qkv,
                                              u16* __restrict__ ao)
{
    __shared__ u16 kvh[64][258];
    __shared__ float sc[64][67];
    const int t = threadIdx.x;
    const size_t base = (size_t)blockIdx.x * 64;

    for (int p = t; p < 8192; p += 256) {
        const int r = p >> 7, c2 = p & 127;
        *(u32*)&kvh[r][c2 * 2] = *(const u32*)(qkv + (base + r) * 768 + 256 + c2 * 2);
    }
    __syncthreads();
    {
        const int i = t >> 2, jb = (t & 3) * 16;
        float acc[16] = {};
        const u16* qp = qkv + (base + i) * 768;
        for (int c = 0; c < 256; c += 2) {
            const u32 qu = *(const u32*)(qp + c);
            const float q0 = blo(qu), q1 = bhi(qu);
            #pragma unroll
            for (int j = 0; j < 16; ++j) {
                const u32 ku = *(const u32*)&kvh[jb + j][c];
                acc[j] = fmaf(q0, blo(ku), acc[j]);
                acc[j] = fmaf(q1, bhi(ku), acc[j]);
            }
        }
        #pragma unroll
        for (int j = 0; j < 16; ++j) sc[i][jb + j] = acc[j] * 0.0625f;
    }
    __syncthreads();
    for (int p = t; p < 8192; p += 256) {
        const int r = p >> 7, c2 = p & 127;
        *(u32*)&kvh[r][c2 * 2] = *(const u32*)(qkv + (base + r) * 768 + 512 + c2 * 2);
    }
    if (t < 64) {
        float mx = -1e30f;
        for (int j = 0; j < 64; ++j) mx = fmaxf(mx, sc[t][j]);
        float s = 0.f;
        for (int j = 0; j < 64; ++j) {
            const float e = expf(sc[t][j] - mx);
            sc[t][j] = e; s += e;
        }
        const float inv = 1.f / s;
        for (int j = 0; j < 64; ++j) sc[t][j] *= inv;
    }
    __syncthreads();
    {
        const int ch = t & 127;
        const int ih = (t >> 7) * 32;
        for (int i2 = ih; i2 < ih + 32; ++i2) {
            float a0 = 0.f, a1 = 0.f;
            #pragma unroll
            for (int j = 0; j < 64; ++j) {
                const float p = sc[i2][j];
                const u32 vu = *(const u32*)&kvh[j][ch * 2];
                a0 = fmaf(p, blo(vu), a0);
                a1 = fmaf(p, bhi(vu), a1);
            }
            const u32 o = ((u32)fbf(a1) << 16) | fbf(a0);
            *(u32*)(ao + (base + i2) * 256 + ch * 2) = o;
        }
    }
}

// ---------------------------------------------------------------------------
// Depthwise 3x3 + bias + GELU, channel-last bf16 (M,512), 8 channels/thread.
// Per wave: n is uniform (boundary branches non-divergent), the 64 lanes span
// all 64 channel-groups -> every tap load is a 1 KiB coalesced transaction.
__global__ __launch_bounds__(256) void dwconv_v8(const u16* __restrict__ h1,
                                                 const float* __restrict__ w,
                                                 const float* __restrict__ b2,
                                                 u16* __restrict__ h2)
{
    const int g = blockIdx.x * 256 + threadIdx.x;   // over M*64 groups
    const int cb = (g & 63) * 8;                    // base channel of group
    const int n = g >> 6;
    const int x = n & 127, y = (n >> 7) & 127, b = n >> 14;
    const u16* in = h1 + (((size_t)b << 14) << 9);  // batch base (n*512)

    // 8 channels x 9 taps of weights: 72 consecutive floats, 16B-aligned
    float wr[72];
    #pragma unroll
    for (int i = 0; i < 18; ++i)
        *(float4*)&wr[i * 4] = *(const float4*)(w + cb * 9 + i * 4);

    float acc[8];
    {
        const float4 bl = *(const float4*)(b2 + cb);
        const float4 bh = *(const float4*)(b2 + cb + 4);
        acc[0] = bl.x; acc[1] = bl.y; acc[2] = bl.z; acc[3] = bl.w;
        acc[4] = bh.x; acc[5] = bh.y; acc[6] = bh.z; acc[7] = bh.w;
    }

    #pragma unroll
    for (int dy = -1; dy <= 1; ++dy) {
        const int yy = y + dy;
        if (yy < 0 || yy > 127) continue;           // wave-uniform
        #pragma unroll
        for (int dx = -1; dx <= 1; ++dx) {
            const int xx = x + dx;
            if (xx < 0 || xx > 127) continue;       // wave-uniform
            const int tap = (dy + 1) * 3 + (dx + 1);
            const uint4 v = *(const uint4*)(in + (size_t)(((yy << 7) + xx) << 9) + cb);
            const u32 p[4] = { v.x, v.y, v.z, v.w };
            #pragma unroll
            for (int q = 0; q < 4; ++q) {
                acc[2 * q + 0] = fmaf(wr[(2 * q + 0) * 9 + tap], blo(p[q]), acc[2 * q + 0]);
                acc[2 * q + 1] = fmaf(wr[(2 * q + 1) * 9 + tap], bhi(p[q]), acc[2 * q + 1]);
            }
        }
    }

    uint4 o;
    u32* op = (u32*)&o;
    #pragma unroll
    for (int q = 0; q < 4; ++q) {
        const float g0 = gelu_f(acc[2 * q + 0]);
        const float g1 = gelu_f(acc[2 * q + 1]);
        op[q] = ((u32)fbf(g1) << 16) | fbf(g0);
    }
    *(uint4*)(h2 + (size_t)n * 512 + cb) = o;
}

// ---------------------------------------------------------------------------
extern "C" void kernel_launch(void* const* d_in, const int* in_sizes, int n_in,
                              void* d_out, int out_size, void* d_ws, size_t ws_size,
                              hipStream_t stream)
{
    (void)in_sizes; (void)n_in; (void)out_size; (void)ws_size;
    const float* x     = (const float*)d_in[0];
    const float* ln1s  = (const float*)d_in[1];
    const float* ln1b  = (const float*)d_in[2];
    const float* qkvw  = (const float*)d_in[3];
    const float* qkvb  = (const float*)d_in[4];
    const float* projw = (const float*)d_in[5];
    const float* projb = (const float*)d_in[6];
    const float* ln2s  = (const float*)d_in[7];
    const float* ln2b  = (const float*)d_in[8];
    const float* w1    = (const float*)d_in[9];
    const float* b1    = (const float*)d_in[10];
    const float* w2    = (const float*)d_in[11];
    const float* b2    = (const float*)d_in[12];
    const float* w3    = (const float*)d_in[13];
    const float* b3    = (const float*)d_in[14];
    float* out = (float*)d_out;
    char* ws = (char*)d_ws;

    u16* XLN = (u16*)(ws);
    u16* QKV = (u16*)(ws + (size_t)67108864);
    u16* AO  = (u16*)(ws + (size_t)268435456);
    u16* YLN = XLN;
    u16* H1  = (u16*)(ws + (size_t)67108864);
    u16* H2  = (u16*)(ws + (size_t)201326592);

    ln_k<<<dim3(MDIM / 256), dim3(256), 0, stream>>>(x, ln1s, ln1b, XLN);
    mgemm<256, 768, 0><<<dim3(1024, 12), dim3(256), 0, stream>>>(XLN, qkvw, qkvb, nullptr, nullptr, QKV);
    attn_k<<<dim3(MDIM / 64), dim3(256), 0, stream>>>(QKV, AO);
    mgemm<256, 256, 1><<<dim3(1024, 4), dim3(256), 0, stream>>>(AO, projw, projb, x, out, nullptr);
    ln_k<<<dim3(MDIM / 256), dim3(256), 0, stream>>>(out, ln2s, ln2b, YLN);
    mgemm<256, 512, 2><<<dim3(1024, 8), dim3(256), 0, stream>>>(YLN, w1, b1, nullptr, nullptr, H1);
    dwconv_v8<<<dim3((MDIM * 64) / 256), dim3(256), 0, stream>>>(H1, w2, b2, H2);
    mgemm<512, 256, 3><<<dim3(1024, 4), dim3(256), 0, stream>>>(H2, w3, b3, out, out, nullptr);
}